// Round 1
// baseline (1537.563 us; speedup 1.0000x reference)
//
#include <hip/hip_runtime.h>

// Asym_Attention on MI355X (gfx950).
// Pipeline: [gemm_qkv (bf16 hi/lo MFMA)] -> q,k,vT bf16 in ws
//           [attn flash-style, MFMA 16x16x32] -> oh/ol (hi/lo bf16) in ws
//           [gemm_proj (A=hi/lo bf16, B=f32->hi/lo)] -> d_out f32
// ws layout (u16 elements, SZ = 1536*384*64 = 37,748,736 each):
//   q_ | k_ | v_ (transposed [bh][d][tok]) | oh | ol   => 377,487,360 bytes total.

typedef unsigned short u16;
typedef unsigned int   u32;
typedef float f32x4 __attribute__((ext_vector_type(4)));
typedef short bfrag  __attribute__((ext_vector_type(8)));   // 8 bf16 (4 VGPRs)

__device__ __forceinline__ f32x4 mfma16(bfrag a, bfrag b, f32x4 c) {
  return __builtin_amdgcn_mfma_f32_16x16x32_bf16(a, b, c, 0, 0, 0);
}

__device__ __forceinline__ u16 bf16_rn(float f) {
  u32 u = __builtin_bit_cast(u32, f);
  return (u16)((u + 0x7fffu + ((u >> 16) & 1u)) >> 16);
}
__device__ __forceinline__ float bf16_trunc_f(float a) {
  return __builtin_bit_cast(float, __builtin_bit_cast(u32, a) & 0xffff0000u);
}
__device__ __forceinline__ u32 pack_rtz(float a, float b) {
  return (__builtin_bit_cast(u32, a) >> 16) | (__builtin_bit_cast(u32, b) & 0xffff0000u);
}
__device__ __forceinline__ u32 pack_rn(float a, float b) {
  u32 ua = __builtin_bit_cast(u32, a), ub = __builtin_bit_cast(u32, b);
  ua = (ua + 0x7fffu + ((ua >> 16) & 1u)) >> 16;
  ub = (ub + 0x7fffu + ((ub >> 16) & 1u)) & 0xffff0000u;
  return ua | ub;
}

// Stage one 128x64 f32 tile as hi/lo bf16 into swizzled LDS.
// thread covers row r (0..127), half (0..1): 32 consecutive f32.
// LDS granule layout: row*64 u16 + (glin ^ (row&7))*8, glin = byte_col/16.
__device__ __forceinline__ void stage_f32_hilo(const float* src, u16* hiT, u16* loT,
                                               int r, int half) {
#pragma unroll
  for (int p = 0; p < 4; p++) {
    float4 v0 = *(const float4*)(src + p * 8);
    float4 v1 = *(const float4*)(src + p * 8 + 4);
    u32 h0 = pack_rtz(v0.x, v0.y), h1 = pack_rtz(v0.z, v0.w);
    u32 h2 = pack_rtz(v1.x, v1.y), h3 = pack_rtz(v1.z, v1.w);
    float a0 = v0.x - bf16_trunc_f(v0.x), a1 = v0.y - bf16_trunc_f(v0.y);
    float a2 = v0.z - bf16_trunc_f(v0.z), a3 = v0.w - bf16_trunc_f(v0.w);
    float a4 = v1.x - bf16_trunc_f(v1.x), a5 = v1.y - bf16_trunc_f(v1.y);
    float a6 = v1.z - bf16_trunc_f(v1.z), a7 = v1.w - bf16_trunc_f(v1.w);
    u32 L0 = pack_rtz(a0, a1), L1 = pack_rtz(a2, a3);
    u32 L2 = pack_rtz(a4, a5), L3 = pack_rtz(a6, a7);
    int g = (half * 4 + p) ^ (r & 7);
    *(uint4*)&hiT[r * 64 + g * 8] = make_uint4(h0, h1, h2, h3);
    *(uint4*)&loT[r * 64 + g * 8] = make_uint4(L0, L1, L2, L3);
  }
}

// AMODE 0: A from f32 (two segments x_v|x_i), convert on the fly.
// AMODE 1: A from pre-split hi/lo bf16 (oh/ol).
// EPI 0: scatter q (scaled), k, vT as bf16.  EPI 1: f32 out + bias.
template <int AMODE, int EPI, int NBLK>
__global__ __launch_bounds__(256, 2)
void gemm_kernel(const float* __restrict__ A0, const float* __restrict__ A1,
                 const u16* __restrict__ Ahg, const u16* __restrict__ Alg,
                 const float* __restrict__ Bg, const float* __restrict__ bias,
                 u16* __restrict__ qo, u16* __restrict__ ko, u16* __restrict__ vo,
                 float* __restrict__ outp) {
  __shared__ u16 AhT[128 * 64];
  __shared__ u16 AlT[128 * 64];
  __shared__ u16 BhT[128 * 64];
  __shared__ u16 BlT[128 * 64];

  const int bid = blockIdx.x;
  const int nb = bid % NBLK, mb = bid / NBLK;
  const int t = threadIdx.x;
  const int lane = t & 63;
  const int wv = t >> 6, wm = wv >> 1, wn = wv & 1;
  const int l15 = lane & 15, lg = lane >> 4;
  const int r2 = t >> 1, half = t & 1;

  f32x4 acc[4][4];
#pragma unroll
  for (int i = 0; i < 4; i++)
#pragma unroll
    for (int j = 0; j < 4; j++) acc[i][j] = (f32x4){0.f, 0.f, 0.f, 0.f};

  for (int k0 = 0; k0 < 768; k0 += 64) {
    if constexpr (AMODE == 0) {
      int row = mb * 128 + r2;
      const float* arow = (row < 24576) ? (A0 + (size_t)row * 768)
                                        : (A1 + (size_t)(row - 24576) * 768);
      stage_f32_hilo(arow + k0 + half * 32, AhT, AlT, r2, half);
    } else {
      const u16* hs = Ahg + (size_t)(mb * 128 + r2) * 768 + k0 + half * 32;
      const u16* ls = Alg + (size_t)(mb * 128 + r2) * 768 + k0 + half * 32;
#pragma unroll
      for (int p = 0; p < 4; p++) {
        uint4 hv = *(const uint4*)(hs + p * 8);
        uint4 lv = *(const uint4*)(ls + p * 8);
        int g = (half * 4 + p) ^ (r2 & 7);
        *(uint4*)&AhT[r2 * 64 + g * 8] = hv;
        *(uint4*)&AlT[r2 * 64 + g * 8] = lv;
      }
    }
    stage_f32_hilo(Bg + (size_t)(nb * 128 + r2) * 768 + k0 + half * 32, BhT, BlT, r2, half);
    __syncthreads();

#pragma unroll
    for (int ks = 0; ks < 2; ks++) {
      bfrag ah[4], al[4], bh[4], bl[4];
#pragma unroll
      for (int ms = 0; ms < 4; ms++) {
        int row = wm * 64 + ms * 16 + l15;
        int g = (ks * 4 + lg) ^ (row & 7);
        ah[ms] = *(const bfrag*)&AhT[row * 64 + g * 8];
        al[ms] = *(const bfrag*)&AlT[row * 64 + g * 8];
      }
#pragma unroll
      for (int ns = 0; ns < 4; ns++) {
        int row = wn * 64 + ns * 16 + l15;
        int g = (ks * 4 + lg) ^ (row & 7);
        bh[ns] = *(const bfrag*)&BhT[row * 64 + g * 8];
        bl[ns] = *(const bfrag*)&BlT[row * 64 + g * 8];
      }
#pragma unroll
      for (int ms = 0; ms < 4; ms++)
#pragma unroll
        for (int ns = 0; ns < 4; ns++) {
          acc[ms][ns] = mfma16(ah[ms], bh[ns], acc[ms][ns]);
          acc[ms][ns] = mfma16(al[ms], bh[ns], acc[ms][ns]);
          acc[ms][ns] = mfma16(ah[ms], bl[ns], acc[ms][ns]);
        }
    }
    __syncthreads();
  }

#pragma unroll
  for (int ms = 0; ms < 4; ms++) {
#pragma unroll
    for (int ns = 0; ns < 4; ns++) {
      int n = nb * 128 + wn * 64 + ns * 16 + l15;
      float bv = bias[n];
#pragma unroll
      for (int r = 0; r < 4; r++) {
        int m = mb * 128 + wm * 64 + ms * 16 + lg * 4 + r;
        float f = acc[ms][ns][r] + bv;
        if constexpr (EPI == 0) {
          int which = n / 768;
          int hh = (n % 768) / 64;
          int d = n % 64;
          int b2i = m / 384, tok = m % 384;
          int bhn = b2i * 12 + hh;
          if (which == 0) {
            qo[((size_t)bhn * 384 + tok) * 64 + d] = bf16_rn(f * 0.125f);  // fold softmax scale
          } else if (which == 1) {
            ko[((size_t)bhn * 384 + tok) * 64 + d] = bf16_rn(f);
          } else {
            vo[((size_t)bhn * 64 + d) * 384 + tok] = bf16_rn(f);           // V transposed
          }
        } else {
          outp[(size_t)m * 768 + n] = f;
        }
      }
    }
  }
}

// Flash attention. One workgroup = (bh, 64-row q-block). 4 waves x 16 q-rows.
// mt rows (tok<128): keys = own mt (128).  s rows: keys = mtV + mtI + own s (512).
__global__ __launch_bounds__(256, 2)
void attn_kernel(const u16* __restrict__ q, const u16* __restrict__ k,
                 const u16* __restrict__ vT,
                 u16* __restrict__ oh, u16* __restrict__ ol) {
  __shared__ u16 KL[64 * 64];
  __shared__ u16 VL[64 * 64];
  __shared__ float PL[4][16 * 68];

  const int bid = blockIdx.x;
  const int qb = bid % 6, bh = bid / 6;
  const int b2i = bh / 12, hh = bh % 12;
  const int q0 = qb * 64;
  const int t = threadIdx.x;
  const int lane = t & 63, wv = t >> 6;
  const int l15 = lane & 15, lg = lane >> 4;
  const int rs = t >> 2, gq = (t & 3) * 2;

  const u16* qp = q + ((size_t)bh * 384 + q0 + wv * 16 + l15) * 64 + lg * 8;
  bfrag qf0 = *(const bfrag*)(qp);
  bfrag qf1 = *(const bfrag*)(qp + 32);

  f32x4 o[4];
#pragma unroll
  for (int i = 0; i < 4; i++) o[i] = (f32x4){0.f, 0.f, 0.f, 0.f};
  float m_run[4], l_run[4];
#pragma unroll
  for (int r = 0; r < 4; r++) { m_run[r] = -1e30f; l_run[r] = 0.f; }

  const int nblk = (q0 < 128) ? 2 : 8;

  for (int kb = 0; kb < nblk; kb++) {
    int src_bh, row0;
    if (q0 < 128)      { src_bh = bh;                          row0 = kb * 64; }
    else if (kb < 2)   { src_bh = (b2i & 63) * 12 + hh;        row0 = kb * 64; }
    else if (kb < 4)   { src_bh = ((b2i & 63) + 64) * 12 + hh; row0 = (kb - 2) * 64; }
    else               { src_bh = bh;                          row0 = 128 + (kb - 4) * 64; }

    {  // stage K (rows=keys) and V^T (rows=d) with XOR-swizzled granules
      const u16* krow = k + ((size_t)src_bh * 384 + row0 + rs) * 64 + gq * 8;
      uint4 ka = *(const uint4*)(krow);
      uint4 kbv = *(const uint4*)(krow + 8);
      *(uint4*)&KL[rs * 64 + ((gq ^ (rs & 7)) * 8)] = ka;
      *(uint4*)&KL[rs * 64 + (((gq + 1) ^ (rs & 7)) * 8)] = kbv;
      const u16* vrow = vT + ((size_t)src_bh * 64 + rs) * 384 + row0 + gq * 8;
      uint4 va = *(const uint4*)(vrow);
      uint4 vb = *(const uint4*)(vrow + 8);
      *(uint4*)&VL[rs * 64 + ((gq ^ (rs & 7)) * 8)] = va;
      *(uint4*)&VL[rs * 64 + (((gq + 1) ^ (rs & 7)) * 8)] = vb;
    }
    __syncthreads();

    f32x4 S[4];
#pragma unroll
    for (int nt = 0; nt < 4; nt++) S[nt] = (f32x4){0.f, 0.f, 0.f, 0.f};
#pragma unroll
    for (int nt = 0; nt < 4; nt++) {
      int row = nt * 16 + l15;
      bfrag k0f = *(const bfrag*)&KL[row * 64 + ((lg ^ (row & 7)) * 8)];
      bfrag k1f = *(const bfrag*)&KL[row * 64 + (((4 + lg) ^ (row & 7)) * 8)];
      S[nt] = mfma16(qf0, k0f, S[nt]);
      S[nt] = mfma16(qf1, k1f, S[nt]);
    }

    float ps[4];
#pragma unroll
    for (int r = 0; r < 4; r++) {
      float v = fmaxf(fmaxf(S[0][r], S[1][r]), fmaxf(S[2][r], S[3][r]));
      v = fmaxf(v, __shfl_xor(v, 1));
      v = fmaxf(v, __shfl_xor(v, 2));
      v = fmaxf(v, __shfl_xor(v, 4));
      v = fmaxf(v, __shfl_xor(v, 8));
      float nm = fmaxf(m_run[r], v);
      float fac = __expf(m_run[r] - nm);
      m_run[r] = nm;
      l_run[r] *= fac;
      o[0][r] *= fac; o[1][r] *= fac; o[2][r] *= fac; o[3][r] *= fac;
      ps[r] = 0.f;
    }
#pragma unroll
    for (int nt = 0; nt < 4; nt++)
#pragma unroll
      for (int r = 0; r < 4; r++) {
        float p = __expf(S[nt][r] - m_run[r]);
        ps[r] += p;
        PL[wv][(lg * 4 + r) * 68 + nt * 16 + l15] = p;
      }
#pragma unroll
    for (int r = 0; r < 4; r++) {
      float v = ps[r];
      v += __shfl_xor(v, 1); v += __shfl_xor(v, 2);
      v += __shfl_xor(v, 4); v += __shfl_xor(v, 8);
      l_run[r] += v;
    }
    asm volatile("s_waitcnt lgkmcnt(0)" ::: "memory");

    bfrag pf[2];
#pragma unroll
    for (int ks = 0; ks < 2; ks++) {
      const float* pr = &PL[wv][l15 * 68 + lg * 8 + ks * 32];
      float4 x0 = *(const float4*)(pr);
      float4 x1 = *(const float4*)(pr + 4);
      union { bfrag v; u32 w[4]; } pu;
      pu.w[0] = pack_rn(x0.x, x0.y);
      pu.w[1] = pack_rn(x0.z, x0.w);
      pu.w[2] = pack_rn(x1.x, x1.y);
      pu.w[3] = pack_rn(x1.z, x1.w);
      pf[ks] = pu.v;
    }
#pragma unroll
    for (int dt = 0; dt < 4; dt++) {
      int row = dt * 16 + l15;
      bfrag v0f = *(const bfrag*)&VL[row * 64 + ((lg ^ (row & 7)) * 8)];
      bfrag v1f = *(const bfrag*)&VL[row * 64 + (((4 + lg) ^ (row & 7)) * 8)];
      o[dt] = mfma16(pf[0], v0f, o[dt]);
      o[dt] = mfma16(pf[1], v1f, o[dt]);
    }
    __syncthreads();
  }

#pragma unroll
  for (int r = 0; r < 4; r++) l_run[r] = 1.f / l_run[r];
#pragma unroll
  for (int dt = 0; dt < 4; dt++)
#pragma unroll
    for (int r = 0; r < 4; r++) {
      float f = o[dt][r] * l_run[r];
      int tok = q0 + wv * 16 + lg * 4 + r;
      int col = hh * 64 + dt * 16 + l15;
      size_t idx = ((size_t)b2i * 384 + tok) * 768 + col;
      oh[idx] = (u16)(__builtin_bit_cast(u32, f) >> 16);
      ol[idx] = bf16_rn(f - bf16_trunc_f(f));
    }
}

extern "C" void kernel_launch(void* const* d_in, const int* in_sizes, int n_in,
                              void* d_out, int out_size, void* d_ws, size_t ws_size,
                              hipStream_t stream) {
  const float* xv    = (const float*)d_in[0];
  const float* xi    = (const float*)d_in[1];
  const float* wqkv  = (const float*)d_in[2];
  const float* bqkv  = (const float*)d_in[3];
  const float* wproj = (const float*)d_in[4];
  const float* bproj = (const float*)d_in[5];
  float* outp = (float*)d_out;

  const size_t SZ = (size_t)1536 * 384 * 64;     // 37,748,736 u16 per array
  const size_t WS_NEED = 5 * SZ * sizeof(u16);   // 377,487,360 B
  if (ws_size < WS_NEED) {  // clean failure instead of OOB write
    hipMemsetAsync(d_out, 0, (size_t)out_size * sizeof(float), stream);
    return;
  }
  u16* q_ = (u16*)d_ws;
  u16* k_ = q_ + SZ;
  u16* v_ = k_ + SZ;
  u16* oh = v_ + SZ;
  u16* ol = oh + SZ;

  gemm_kernel<0, 0, 18><<<dim3(384 * 18), 256, 0, stream>>>(
      xv, xi, nullptr, nullptr, wqkv, bqkv, q_, k_, v_, nullptr);
  attn_kernel<<<dim3(1536 * 6), 256, 0, stream>>>(q_, k_, v_, oh, ol);
  gemm_kernel<1, 1, 6><<<dim3(384 * 6), 256, 0, stream>>>(
      nullptr, nullptr, oh, ol, wproj, bproj, nullptr, nullptr, nullptr, outp);
}

// Round 2
// 843.487 us; speedup vs baseline: 1.8229x; 1.8229x over previous
//
#include <hip/hip_runtime.h>

// Asym_Attention on MI355X (gfx950) — round 2.
// Pipeline: [convert: f32 -> bf16 (Ah, Bh, Ph)]
//           [gemm_bf16<EPI=0>: qkv = Ah @ Bh^T] -> q(scaled),k,vT bf16
//           [attn flash-style 16x16x32 MFMA]    -> oh bf16 (merged heads)
//           [gemm_bf16<EPI=1>: out = oh @ Ph^T + bias] -> d_out f32
// ws (u16 elems): Ah(37.75M, reused as oh) | Bh(1.77M) | Ph(0.59M) | q|k|vT (3x37.75M)
//   total 306,708,480 B  (< round-1's proven 377 MB)

typedef unsigned short u16;
typedef unsigned int   u32;
typedef float f32x4 __attribute__((ext_vector_type(4)));
typedef short bfrag  __attribute__((ext_vector_type(8)));   // 8 bf16 (4 VGPRs)

__device__ __forceinline__ f32x4 mfma16(bfrag a, bfrag b, f32x4 c) {
  return __builtin_amdgcn_mfma_f32_16x16x32_bf16(a, b, c, 0, 0, 0);
}
__device__ __forceinline__ u16 bf16_rn(float f) {
  u32 u = __builtin_bit_cast(u32, f);
  return (u16)((u + 0x7fffu + ((u >> 16) & 1u)) >> 16);
}
__device__ __forceinline__ u32 pack_rn(float a, float b) {
  u32 ua = __builtin_bit_cast(u32, a), ub = __builtin_bit_cast(u32, b);
  ua = (ua + 0x7fffu + ((ua >> 16) & 1u)) >> 16;
  ub = (ub + 0x7fffu + ((ub >> 16) & 1u)) & 0xffff0000u;
  return ua | ub;
}

// async global->LDS, 16B per lane. LDS dest is wave-uniform base + lane*16 (HW rule).
__device__ __forceinline__ void gll16(const u16* g, u16* l) {
  __builtin_amdgcn_global_load_lds((const __attribute__((address_space(1))) void*)g,
                                   (__attribute__((address_space(3))) void*)l, 16, 0, 0);
}

// ---------------- convert: f32 -> bf16 (rn) ----------------
__global__ __launch_bounds__(256)
void convert_kernel(const float* __restrict__ xv, const float* __restrict__ xi,
                    const float* __restrict__ wq, const float* __restrict__ wp,
                    u16* __restrict__ Ah, u16* __restrict__ Bh, u16* __restrict__ Ph) {
  const size_t NA = (size_t)49152 * 768, NB = (size_t)2304 * 768, NP = (size_t)768 * 768;
  const size_t HALF = (size_t)24576 * 768;
  size_t tid = (size_t)blockIdx.x * 256 + threadIdx.x;
  size_t stride = (size_t)gridDim.x * 256;
  for (size_t i = tid; i < NA / 8; i += stride) {
    size_t e = i * 8;
    const float* s = (e < HALF) ? (xv + e) : (xi + (e - HALF));
    float4 a = ((const float4*)s)[0], b = ((const float4*)s)[1];
    ((uint4*)Ah)[i] = make_uint4(pack_rn(a.x, a.y), pack_rn(a.z, a.w),
                                 pack_rn(b.x, b.y), pack_rn(b.z, b.w));
  }
  for (size_t i = tid; i < NB / 8; i += stride) {
    float4 a = ((const float4*)(wq + i * 8))[0], b = ((const float4*)(wq + i * 8))[1];
    ((uint4*)Bh)[i] = make_uint4(pack_rn(a.x, a.y), pack_rn(a.z, a.w),
                                 pack_rn(b.x, b.y), pack_rn(b.z, b.w));
  }
  for (size_t i = tid; i < NP / 8; i += stride) {
    float4 a = ((const float4*)(wp + i * 8))[0], b = ((const float4*)(wp + i * 8))[1];
    ((uint4*)Ph)[i] = make_uint4(pack_rn(a.x, a.y), pack_rn(a.z, a.w),
                                 pack_rn(b.x, b.y), pack_rn(b.z, b.w));
  }
}

// ---------------- bf16 GEMM, m97 structure ----------------
// C[128x128] per block, BK=64, 4 waves (2x2 of 64x64), 16x16x32 MFMA.
// LDS tiles [128 rows][64 cols bf16], granule(16B)-XOR-swizzled: granule slot
// g holds source granule g^(row&7). Staged via global_load_lds with the
// inverse permutation applied to the per-lane GLOBAL address (LDS stays linear).
// EPI 0: scatter q(*0.125)/k/vT bf16.   EPI 1: f32 out + bias.
template <int EPI, int NBLK>
__global__ __launch_bounds__(256, 3)
void gemm_bf16(const u16* __restrict__ Ag, const u16* __restrict__ Bg,
               const float* __restrict__ bias,
               u16* __restrict__ qo, u16* __restrict__ ko, u16* __restrict__ vo,
               float* __restrict__ outp) {
  __shared__ u16 AT[128 * 64];
  __shared__ u16 BT[128 * 64];

  // XCD-aware swizzle (gridDim.x % 8 == 0): contiguous chunk per XCD.
  const int cpx = gridDim.x >> 3;
  const int bid = (blockIdx.x & 7) * cpx + (blockIdx.x >> 3);
  const int nb = bid % NBLK, mb = bid / NBLK;
  const int t = threadIdx.x;
  const int lane = t & 63;
  const int wv = t >> 6, wm = wv >> 1, wn = wv & 1;
  const int l15 = lane & 15, lg = lane >> 4;

  // staging addresses: wave wv covers rows [wv*32, wv*32+32), 4 instr x 8 rows.
  const int lr = lane >> 3;                 // row within 8-row group; r&7 == lr
  const int gs = (lane & 7) ^ lr;           // pre-swizzled source granule
  const u16* asrc = Ag + ((size_t)(mb * 128 + wv * 32 + lr)) * 768 + gs * 8;
  const u16* bsrc = Bg + ((size_t)(nb * 128 + wv * 32 + lr)) * 768 + gs * 8;

  f32x4 acc[4][4];
#pragma unroll
  for (int i = 0; i < 4; i++)
#pragma unroll
    for (int j = 0; j < 4; j++) acc[i][j] = (f32x4){0.f, 0.f, 0.f, 0.f};

  for (int k0 = 0; k0 < 768; k0 += 64) {
#pragma unroll
    for (int i = 0; i < 4; i++) {
      gll16(asrc + (size_t)i * 8 * 768 + k0, AT + (wv * 32 + i * 8) * 64);
      gll16(bsrc + (size_t)i * 8 * 768 + k0, BT + (wv * 32 + i * 8) * 64);
    }
    __syncthreads();   // compiler drains vmcnt before barrier

#pragma unroll
    for (int ks = 0; ks < 2; ks++) {
      bfrag af[4], bf[4];
#pragma unroll
      for (int ms = 0; ms < 4; ms++) {
        int row = wm * 64 + ms * 16 + l15;
        af[ms] = *(const bfrag*)&AT[row * 64 + (((ks * 4 + lg) ^ (row & 7)) * 8)];
      }
#pragma unroll
      for (int ns = 0; ns < 4; ns++) {
        int row = wn * 64 + ns * 16 + l15;
        bf[ns] = *(const bfrag*)&BT[row * 64 + (((ks * 4 + lg) ^ (row & 7)) * 8)];
      }
#pragma unroll
      for (int ms = 0; ms < 4; ms++)
#pragma unroll
        for (int ns = 0; ns < 4; ns++)
          acc[ms][ns] = mfma16(af[ms], bf[ns], acc[ms][ns]);
    }
    __syncthreads();
  }

#pragma unroll
  for (int ms = 0; ms < 4; ms++) {
#pragma unroll
    for (int ns = 0; ns < 4; ns++) {
      int n = nb * 128 + wn * 64 + ns * 16 + l15;
      float bv = bias[n];
#pragma unroll
      for (int r = 0; r < 4; r++) {
        int m = mb * 128 + wm * 64 + ms * 16 + lg * 4 + r;
        float f = acc[ms][ns][r] + bv;
        if constexpr (EPI == 0) {
          int which = n / 768;
          int hh = (n % 768) / 64;
          int d = n % 64;
          int b2i = m / 384, tok = m % 384;
          int bhn = b2i * 12 + hh;
          if (which == 0) {
            qo[((size_t)bhn * 384 + tok) * 64 + d] = bf16_rn(f * 0.125f);  // fold softmax scale
          } else if (which == 1) {
            ko[((size_t)bhn * 384 + tok) * 64 + d] = bf16_rn(f);
          } else {
            vo[((size_t)bhn * 64 + d) * 384 + tok] = bf16_rn(f);           // V transposed
          }
        } else {
          outp[(size_t)m * 768 + n] = f;
        }
      }
    }
  }
}

// ---------------- flash attention ----------------
// One workgroup = (bh, 64-row q-block). 4 waves x 16 q-rows. Q in registers,
// K / V^T staged to XOR-swizzled LDS per 64-key block, online softmax.
// mt rows (tok<128): keys = own mt (128).  s rows: keys = mtV + mtI + own s (512).
__global__ __launch_bounds__(256, 2)
void attn_kernel(const u16* __restrict__ q, const u16* __restrict__ k,
                 const u16* __restrict__ vT, u16* __restrict__ oh) {
  __shared__ u16 KL[64 * 64];
  __shared__ u16 VL[64 * 64];
  __shared__ float PL[4][16 * 68];

  const int cpx = gridDim.x >> 3;
  const int bid = (blockIdx.x & 7) * cpx + (blockIdx.x >> 3);
  const int qb = bid % 6, bh = bid / 6;
  const int b2i = bh / 12, hh = bh % 12;
  const int q0 = qb * 64;
  const int t = threadIdx.x;
  const int lane = t & 63, wv = t >> 6;
  const int l15 = lane & 15, lg = lane >> 4;
  const int rs = t >> 2, gq = (t & 3) * 2;

  const u16* qp = q + ((size_t)bh * 384 + q0 + wv * 16 + l15) * 64 + lg * 8;
  bfrag qf0 = *(const bfrag*)(qp);
  bfrag qf1 = *(const bfrag*)(qp + 32);

  f32x4 o[4];
#pragma unroll
  for (int i = 0; i < 4; i++) o[i] = (f32x4){0.f, 0.f, 0.f, 0.f};
  float m_run[4], l_run[4];
#pragma unroll
  for (int r = 0; r < 4; r++) { m_run[r] = -1e30f; l_run[r] = 0.f; }

  const int nblk = (q0 < 128) ? 2 : 8;

  for (int kb = 0; kb < nblk; kb++) {
    int src_bh, row0;
    if (q0 < 128)      { src_bh = bh;                          row0 = kb * 64; }
    else if (kb < 2)   { src_bh = (b2i & 63) * 12 + hh;        row0 = kb * 64; }
    else if (kb < 4)   { src_bh = ((b2i & 63) + 64) * 12 + hh; row0 = (kb - 2) * 64; }
    else               { src_bh = bh;                          row0 = 128 + (kb - 4) * 64; }

    {  // stage K (rows=keys) and V^T (rows=d), XOR-swizzled granules
      const u16* krow = k + ((size_t)src_bh * 384 + row0 + rs) * 64 + gq * 8;
      uint4 ka = *(const uint4*)(krow);
      uint4 kbv = *(const uint4*)(krow + 8);
      *(uint4*)&KL[rs * 64 + ((gq ^ (rs & 7)) * 8)] = ka;
      *(uint4*)&KL[rs * 64 + (((gq + 1) ^ (rs & 7)) * 8)] = kbv;
      const u16* vrow = vT + ((size_t)src_bh * 64 + rs) * 384 + row0 + gq * 8;
      uint4 va = *(const uint4*)(vrow);
      uint4 vb = *(const uint4*)(vrow + 8);
      *(uint4*)&VL[rs * 64 + ((gq ^ (rs & 7)) * 8)] = va;
      *(uint4*)&VL[rs * 64 + (((gq + 1) ^ (rs & 7)) * 8)] = vb;
    }
    __syncthreads();

    f32x4 S[4];
#pragma unroll
    for (int nt = 0; nt < 4; nt++) S[nt] = (f32x4){0.f, 0.f, 0.f, 0.f};
#pragma unroll
    for (int nt = 0; nt < 4; nt++) {
      int row = nt * 16 + l15;
      bfrag k0f = *(const bfrag*)&KL[row * 64 + ((lg ^ (row & 7)) * 8)];
      bfrag k1f = *(const bfrag*)&KL[row * 64 + (((4 + lg) ^ (row & 7)) * 8)];
      S[nt] = mfma16(qf0, k0f, S[nt]);
      S[nt] = mfma16(qf1, k1f, S[nt]);
    }

    float ps[4];
#pragma unroll
    for (int r = 0; r < 4; r++) {
      float v = fmaxf(fmaxf(S[0][r], S[1][r]), fmaxf(S[2][r], S[3][r]));
      v = fmaxf(v, __shfl_xor(v, 1));
      v = fmaxf(v, __shfl_xor(v, 2));
      v = fmaxf(v, __shfl_xor(v, 4));
      v = fmaxf(v, __shfl_xor(v, 8));
      float nm = fmaxf(m_run[r], v);
      float fac = __expf(m_run[r] - nm);
      m_run[r] = nm;
      l_run[r] *= fac;
      o[0][r] *= fac; o[1][r] *= fac; o[2][r] *= fac; o[3][r] *= fac;
      ps[r] = 0.f;
    }
#pragma unroll
    for (int nt = 0; nt < 4; nt++)
#pragma unroll
      for (int r = 0; r < 4; r++) {
        float p = __expf(S[nt][r] - m_run[r]);
        ps[r] += p;
        PL[wv][(lg * 4 + r) * 68 + nt * 16 + l15] = p;
      }
#pragma unroll
    for (int r = 0; r < 4; r++) {
      float v = ps[r];
      v += __shfl_xor(v, 1); v += __shfl_xor(v, 2);
      v += __shfl_xor(v, 4); v += __shfl_xor(v, 8);
      l_run[r] += v;
    }
    asm volatile("s_waitcnt lgkmcnt(0)" ::: "memory");

    bfrag pf[2];
#pragma unroll
    for (int ks = 0; ks < 2; ks++) {
      const float* pr = &PL[wv][l15 * 68 + lg * 8 + ks * 32];
      float4 x0 = *(const float4*)(pr);
      float4 x1 = *(const float4*)(pr + 4);
      union { bfrag v; u32 w[4]; } pu;
      pu.w[0] = pack_rn(x0.x, x0.y);
      pu.w[1] = pack_rn(x0.z, x0.w);
      pu.w[2] = pack_rn(x1.x, x1.y);
      pu.w[3] = pack_rn(x1.z, x1.w);
      pf[ks] = pu.v;
    }
#pragma unroll
    for (int dt = 0; dt < 4; dt++) {
      int row = dt * 16 + l15;
      bfrag v0f = *(const bfrag*)&VL[row * 64 + ((lg ^ (row & 7)) * 8)];
      bfrag v1f = *(const bfrag*)&VL[row * 64 + (((4 + lg) ^ (row & 7)) * 8)];
      o[dt] = mfma16(pf[0], v0f, o[dt]);
      o[dt] = mfma16(pf[1], v1f, o[dt]);
    }
    __syncthreads();
  }

#pragma unroll
  for (int r = 0; r < 4; r++) l_run[r] = 1.f / l_run[r];
#pragma unroll
  for (int dt = 0; dt < 4; dt++)
#pragma unroll
    for (int r = 0; r < 4; r++) {
      float f = o[dt][r] * l_run[r];
      int tok = q0 + wv * 16 + lg * 4 + r;
      int col = hh * 64 + dt * 16 + l15;
      oh[((size_t)b2i * 384 + tok) * 768 + col] = bf16_rn(f);
    }
}

extern "C" void kernel_launch(void* const* d_in, const int* in_sizes, int n_in,
                              void* d_out, int out_size, void* d_ws, size_t ws_size,
                              hipStream_t stream) {
  const float* xv    = (const float*)d_in[0];
  const float* xi    = (const float*)d_in[1];
  const float* wqkv  = (const float*)d_in[2];
  const float* bqkv  = (const float*)d_in[3];
  const float* wproj = (const float*)d_in[4];
  const float* bproj = (const float*)d_in[5];
  float* outp = (float*)d_out;

  const size_t SZ = (size_t)1536 * 384 * 64;   // 37,748,736 u16
  const size_t NB = (size_t)2304 * 768;        //  1,769,472 u16
  const size_t NP = (size_t)768 * 768;         //    589,824 u16
  const size_t WS_NEED = (SZ + NB + NP + 3 * SZ) * sizeof(u16);  // 306,708,480 B
  if (ws_size < WS_NEED) {  // clean failure instead of OOB write
    hipMemsetAsync(d_out, 0, (size_t)out_size * sizeof(float), stream);
    return;
  }
  u16* Ah = (u16*)d_ws;          // reused as oh after QKV gemm
  u16* Bh = Ah + SZ;
  u16* Ph = Bh + NB;
  u16* q_ = Ph + NP;
  u16* k_ = q_ + SZ;
  u16* v_ = k_ + SZ;
  u16* oh = Ah;                  // alias: Ah dead after gemm<0>

  convert_kernel<<<dim3(1024), 256, 0, stream>>>(xv, xi, wqkv, wproj, Ah, Bh, Ph);
  gemm_bf16<0, 18><<<dim3(384 * 18), 256, 0, stream>>>(Ah, Bh, bqkv, q_, k_, v_, nullptr);
  attn_kernel<<<dim3(1536 * 6), 256, 0, stream>>>(q_, k_, v_, oh);
  gemm_bf16<1, 6><<<dim3(384 * 6), 256, 0, stream>>>(oh, Ph, bproj, nullptr, nullptr, nullptr, outp);
}